// Round 4
// baseline (134.597 us; speedup 1.0000x reference)
//
#include <hip/hip_runtime.h>
#include <hip/hip_bf16.h>
#include <stdint.h>

#define BATCH 4096
#define N_TOT 8192
#define D_DIM 256
#define SHIFT 150.0f
#define SQRT2 1.41421356237309515f

typedef __bf16 bf16_t;
typedef bf16_t bf16x8 __attribute__((ext_vector_type(8)));
typedef bf16_t bf16x4 __attribute__((ext_vector_type(4)));
typedef float f32x4 __attribute__((ext_vector_type(4)));

// Fused: bf16 convert (x sqrt2), positive-pair dot partials, Zrow zero-init.
// 1024 blocks x 256 threads; wave w of block b owns row r = b*4+w.
__global__ void k_prep(const float* __restrict__ hi, const float* __restrict__ hj,
                       bf16_t* __restrict__ hb, float* __restrict__ Zrow,
                       float* __restrict__ posPartial) {
  const int wave = threadIdx.x >> 6, lane = threadIdx.x & 63;
  const int r = blockIdx.x * 4 + wave;
  const size_t off = (size_t)r * D_DIM + lane * 4;
  float4 a = *(const float4*)(hi + off);
  float4 b = *(const float4*)(hj + off);

  bf16x4 oa, ob;
  oa[0] = (bf16_t)(a.x * SQRT2); oa[1] = (bf16_t)(a.y * SQRT2);
  oa[2] = (bf16_t)(a.z * SQRT2); oa[3] = (bf16_t)(a.w * SQRT2);
  ob[0] = (bf16_t)(b.x * SQRT2); ob[1] = (bf16_t)(b.y * SQRT2);
  ob[2] = (bf16_t)(b.z * SQRT2); ob[3] = (bf16_t)(b.w * SQRT2);
  *(bf16x4*)(hb + off) = oa;
  *(bf16x4*)(hb + (size_t)BATCH * D_DIM + off) = ob;

  float d = a.x * b.x + a.y * b.y + a.z * b.z + a.w * b.w;
#pragma unroll
  for (int o = 32; o >= 1; o >>= 1) d += __shfl_xor(d, o);
  __shared__ float ps[4];
  if (lane == 0) ps[wave] = d;
  if (threadIdx.x < 8) Zrow[blockIdx.x * 8 + threadIdx.x] = 0.f;
  __syncthreads();
  if (threadIdx.x == 0) posPartial[blockIdx.x] = ps[0] + ps[1] + ps[2] + ps[3];
}

// Upper-triangular 128x128 tiles of sim = hb.hb^T, register-direct MFMA GEMM:
// NO LDS, NO barriers. For C = hb.hb^T, the 16x16x32 A-frag and B-frag have
// identical lane->address maps over hb rows (A[m][k]: m=l16, k=quad*8+j;
// B^T[n][k]: n=l16, same k), so both operands are direct 16B global loads
// from the 4MB L2-resident hb. Waves stream independently; TLP hides L2 lat.
// Fused exp(sim-SHIFT): row sums always, col sums for off-diag (symmetry).
__global__ __launch_bounds__(256, 2) void k_gemm(const bf16_t* __restrict__ hb,
                                                 float* __restrict__ Zrow) {
  // decode linear block id -> (bi <= bj) triangular pair
  const int t = blockIdx.x;
  int bj = (int)((sqrtf(8.0f * (float)t + 1.0f) - 1.0f) * 0.5f);
  while ((bj + 1) * (bj + 2) / 2 <= t) ++bj;
  while (bj * (bj + 1) / 2 > t) --bj;
  const int bi = t - bj * (bj + 1) / 2;
  const int rBase = bi * 128;
  const int cBase = bj * 128;
  const bool diag = (bi == bj);

  const int lane = threadIdx.x & 63;
  const int wave = threadIdx.x >> 6;
  const int wm = wave >> 1, wn = wave & 1;
  const int quad = lane >> 4, l16 = lane & 15;

  // per-lane fragment base pointers (row = base + l16, col chunk = quad*8)
  const bf16_t* aptr = hb + (size_t)(rBase + wm * 64 + l16) * D_DIM + quad * 8;
  const bf16_t* bptr = hb + (size_t)(cBase + wn * 64 + l16) * D_DIM + quad * 8;

  f32x4 acc[4][4];
#pragma unroll
  for (int i = 0; i < 4; ++i)
#pragma unroll
    for (int j = 0; j < 4; ++j) acc[i][j] = (f32x4){0.f, 0.f, 0.f, 0.f};

#pragma unroll
  for (int ks = 0; ks < 8; ++ks) {  // K = 8 x 32
    bf16x8 af[4], bfr[4];
#pragma unroll
    for (int mt = 0; mt < 4; ++mt)
      af[mt] = *(const bf16x8*)(aptr + (size_t)mt * 16 * D_DIM + ks * 32);
#pragma unroll
    for (int nt = 0; nt < 4; ++nt)
      bfr[nt] = *(const bf16x8*)(bptr + (size_t)nt * 16 * D_DIM + ks * 32);
#pragma unroll
    for (int mt = 0; mt < 4; ++mt)
#pragma unroll
      for (int nt = 0; nt < 4; ++nt)
        acc[mt][nt] = __builtin_amdgcn_mfma_f32_16x16x32_bf16(af[mt], bfr[nt],
                                                              acc[mt][nt], 0, 0, 0);
  }

  // epilogue: e = exp(sim - SHIFT); C/D map: col=l16, row=quad*4+reg
  const int rW = rBase + wm * 64 + quad * 4;
  const int cW = cBase + wn * 64 + l16;
  float colAcc[4] = {0.f, 0.f, 0.f, 0.f};
#pragma unroll
  for (int mt = 0; mt < 4; ++mt) {
#pragma unroll
    for (int rg = 0; rg < 4; ++rg) {
      const int rr = rW + mt * 16 + rg;
      float s = 0.f;
#pragma unroll
      for (int nt = 0; nt < 4; ++nt) {
        float e = __expf(acc[mt][nt][rg] - SHIFT);
        if (diag && (rr == cW + nt * 16)) e = 0.f;  // mask self-similarity
        s += e;
        colAcc[nt] += e;
      }
      s += __shfl_xor(s, 1);
      s += __shfl_xor(s, 2);
      s += __shfl_xor(s, 4);
      s += __shfl_xor(s, 8);
      if (l16 == 0) atomicAdd(&Zrow[rr], s);
    }
  }
  if (!diag) {
#pragma unroll
    for (int nt = 0; nt < 4; ++nt) {
      float c = colAcc[nt];
      c += __shfl_xor(c, 16);
      c += __shfl_xor(c, 32);
      if (lane < 16) atomicAdd(&Zrow[cW + nt * 16], c);
    }
  }
}

// One block: loss = mean(log Z + SHIFT) - sum(dot)/2048
__global__ void k_finish(const float* __restrict__ Zrow,
                         const float* __restrict__ posPartial,
                         float* __restrict__ out) {
  const int t = threadIdx.x;  // 0..1023
  float4 z0 = *(const float4*)(Zrow + t * 8);
  float4 z1 = *(const float4*)(Zrow + t * 8 + 4);
  float sl = __logf(z0.x) + __logf(z0.y) + __logf(z0.z) + __logf(z0.w) +
             __logf(z1.x) + __logf(z1.y) + __logf(z1.z) + __logf(z1.w);
  float sp = posPartial[t];
#pragma unroll
  for (int o = 32; o >= 1; o >>= 1) {
    sl += __shfl_xor(sl, o);
    sp += __shfl_xor(sp, o);
  }
  __shared__ float pl[16], pp[16];
  const int wave = t >> 6, lane = t & 63;
  if (lane == 0) { pl[wave] = sl; pp[wave] = sp; }
  __syncthreads();
  if (t == 0) {
    float L = 0.f, P = 0.f;
    for (int i = 0; i < 16; ++i) { L += pl[i]; P += pp[i]; }
    out[0] = L / (float)N_TOT + SHIFT - P / 2048.0f;
  }
}

extern "C" void kernel_launch(void* const* d_in, const int* in_sizes, int n_in,
                              void* d_out, int out_size, void* d_ws, size_t ws_size,
                              hipStream_t stream) {
  const float* hi = (const float*)d_in[0];
  const float* hj = (const float*)d_in[1];
  float* out = (float*)d_out;

  bf16_t* hb = (bf16_t*)d_ws;                                        // 4 MB
  float* Zrow = (float*)((char*)d_ws + (size_t)N_TOT * D_DIM * 2);   // 32 KB
  float* posPartial = Zrow + N_TOT;                                  // 4 KB

  k_prep<<<1024, 256, 0, stream>>>(hi, hj, hb, Zrow, posPartial);
  k_gemm<<<2080, 256, 0, stream>>>(hb, Zrow);
  k_finish<<<1, 1024, 0, stream>>>(Zrow, posPartial, out);
}